// Round 11
// baseline (761.202 us; speedup 1.0000x reference)
//
#include <hip/hip_runtime.h>
#include <hip/hip_fp16.h>

#define NUSERS 60000
#define NITEMS 30000
#define NNODES 90000
#define KDIM 64
#define EH 1000000
#define E2 2000000
#define NBATCH 100000
#define EPSV 1e-8f

#define NB 128      // coarse buckets for CSR builds
#define RPB_I 240   // 128*240 = 30720 >= NITEMS
#define RPB_U 472   // 128*472 = 60416 >= NUSERS
#define CHUNK 2048  // edges per block-round in binA
#define NPAD_I 32768
#define NPAD_U 65536

typedef __attribute__((ext_vector_type(8))) short short8v;
typedef __attribute__((ext_vector_type(4))) float f32x4;
typedef __attribute__((ext_vector_type(4))) unsigned int uint4v;

__device__ inline float4 h4_to_f4(const __half* p) {
    float2 raw = *(const float2*)p;  // single 8B load
    __half2 a = *(__half2*)&raw.x;
    __half2 b = *(__half2*)&raw.y;
    float2 fa = __half22float2(a), fb = __half22float2(b);
    return make_float4(fa.x, fa.y, fb.x, fb.y);
}

// non-temporal 16B load (stream-once data: qp) — keeps xh/v1p/v2p hot in L2
__device__ inline short8v nt_load16(const ushort* p) {
    uint4v v = __builtin_nontemporal_load((const uint4v*)p);
    return *(short8v*)&v;
}

// ---------------- init: zero cnt/deg + xh = fp16(concat(Gu,Gi)) ----------------
__global__ void k_init(const float* __restrict__ Gu, const float* __restrict__ Gi,
                       __half* __restrict__ xh, int* __restrict__ cnt,
                       float* __restrict__ deg) {
    int i = blockIdx.x * 256 + threadIdx.x;
    if (i < NPAD_I + NPAD_U) cnt[i] = 0;
    if (i < NNODES) deg[i] = 0.0f;
    int idx = i * 4;
    if (idx >= NNODES * KDIM) return;
    const float* src = idx < NUSERS * KDIM ? &Gu[idx] : &Gi[idx - NUSERS * KDIM];
    float4 v = *(const float4*)src;
    ((__half2*)xh)[idx / 2]     = __floats2half2_rn(v.x, v.y);
    ((__half2*)xh)[idx / 2 + 1] = __floats2half2_rn(v.z, v.w);
}

// ---------------- CSR builds ----------------
__global__ void k_count2(const int* __restrict__ erow, const int* __restrict__ ecol,
                         int* __restrict__ cntI, int* __restrict__ cntU) {
    int e = blockIdx.x * 256 + threadIdx.x;
    if (e < EH) {
        atomicAdd(&cntI[erow[e] - NUSERS], 1);
        atomicAdd(&cntU[ecol[e]], 1);
    }
}

// grid=2: block 0 scans item counts, block 1 user counts; 8 elems/thread/chunk.
// Each block also writes its bucket cursors (gcur) from its own offsets.
__global__ void k_scan2(const int* __restrict__ cntI, int* __restrict__ ofsI,
                        int* __restrict__ curI, const int* __restrict__ cntU,
                        int* __restrict__ ofsU, int* __restrict__ curU,
                        int* __restrict__ gcurI, int* __restrict__ gcurU) {
    const int* counts; int* offsets; int* cursor; int n;
    if (blockIdx.x == 0) { counts = cntI; offsets = ofsI; cursor = curI; n = NITEMS; }
    else                 { counts = cntU; offsets = ofsU; cursor = curU; n = NUSERS; }
    __shared__ int wsum[17];
    int t = threadIdx.x;
    int lane = t & 63, wid = t >> 6;
    int carry = 0;
    int npad = (n + 8191) & ~8191;
    for (int base = 0; base < npad; base += 8192) {
        int i0 = base + t * 8;
        int4 va = *(const int4*)&counts[i0];      // padded+zeroed, safe
        int4 vb = *(const int4*)&counts[i0 + 4];
        int p0 = va.x, p1 = p0 + va.y, p2 = p1 + va.z, p3 = p2 + va.w;
        int p4 = p3 + vb.x, p5 = p4 + vb.y, p6 = p5 + vb.z, p7 = p6 + vb.w;
        int ws = p7;
#pragma unroll
        for (int o = 1; o < 64; o <<= 1) {
            int u = __shfl_up(ws, o, 64);
            if (lane >= o) ws += u;
        }
        if (lane == 63) wsum[wid] = ws;
        __syncthreads();
        if (wid == 0) {
            int wv = (lane < 16) ? wsum[lane] : 0;
#pragma unroll
            for (int o = 1; o < 16; o <<= 1) {
                int u = __shfl_up(wv, o, 64);
                if (lane >= o) wv += u;
            }
            if (lane < 16) wsum[lane] = wv;
            if (lane == 15) wsum[16] = wv;
        }
        __syncthreads();
        int wbase = (wid > 0) ? wsum[wid - 1] : 0;
        int texcl = carry + wbase + (ws - p7);
        int pre[8] = {0, p0, p1, p2, p3, p4, p5, p6};
#pragma unroll
        for (int k = 0; k < 8; ++k)
            if (i0 + k < n) { offsets[i0 + k] = texcl + pre[k]; cursor[i0 + k] = texcl + pre[k]; }
        carry += wsum[16];
        __syncthreads();
    }
    if (t == 0) offsets[n] = carry;
    __syncthreads();
    if (blockIdx.x == 0) {
        if (t < NB) {
            int r = t * RPB_I; if (r > NITEMS) r = NITEMS;
            gcurI[t] = ofsI[r];
        }
    } else {
        if (t < NB) {
            int r = t * RPB_U; if (r > NUSERS) r = NUSERS;
            gcurU[t] = ofsU[r];
        }
    }
}

// Pass A: LDS counting-sort into NB buckets, coalesced append into bucket regions.
// PHASE 0 (item CSR): row = erow[e]-NUSERS, payload {ecol[e], e}
// PHASE 1 (user CSR): row = ecol[e],        payload {erow[e], inv[e]}
template <int PHASE, int RPBX>
__global__ void k_binA(const int* __restrict__ erow, const int* __restrict__ ecol,
                       const int* __restrict__ inv, int* __restrict__ gcur,
                       int* __restrict__ srow, int2* __restrict__ spay) {
    __shared__ int bcnt[NB];
    __shared__ int bbase[NB];
    __shared__ int bpos[NB];
    __shared__ int bglob[NB];
    __shared__ int wtot[2];
    __shared__ int lrow[CHUNK];
    __shared__ int2 lce[CHUNK];
    int t = threadIdx.x;
    for (int base = blockIdx.x * CHUNK; base < EH; base += gridDim.x * CHUNK) {
        for (int i = t; i < NB; i += 256) bcnt[i] = 0;
        __syncthreads();
        int mr[8], mx[8], my[8], mb[8];
#pragma unroll
        for (int k = 0; k < 8; ++k) {
            int e = base + k * 256 + t;
            if (e < EH) {
                int r, px, py;
                if (PHASE == 0) { r = erow[e] - NUSERS; px = ecol[e]; py = e; }
                else            { r = ecol[e];          px = erow[e]; py = inv[e]; }
                mr[k] = r; mx[k] = px; my[k] = py;
                mb[k] = r / RPBX;
                atomicAdd(&bcnt[mb[k]], 1);
            } else {
                mb[k] = -1;
            }
        }
        __syncthreads();
        if (t < NB) {
            int v = bcnt[t];
            int s = v;
#pragma unroll
            for (int o = 1; o < 64; o <<= 1) {
                int u = __shfl_up(s, o, 64);
                if ((t & 63) >= o) s += u;
            }
            bbase[t] = s - v;
            if ((t & 63) == 63) wtot[t >> 6] = s;
        }
        __syncthreads();
        if (t >= 64 && t < NB) bbase[t] += wtot[0];
        if (t < NB) bpos[t] = 0;
        __syncthreads();
#pragma unroll
        for (int k = 0; k < 8; ++k) {
            if (mb[k] >= 0) {
                int p = bbase[mb[k]] + atomicAdd(&bpos[mb[k]], 1);
                lrow[p] = mr[k];
                lce[p] = make_int2(mx[k], my[k]);
            }
        }
        __syncthreads();
        if (t < NB) bglob[t] = bcnt[t] ? atomicAdd(&gcur[t], bcnt[t]) : 0;
        __syncthreads();
        int total = bbase[NB - 1] + bcnt[NB - 1];
        for (int i = t; i < total; i += 256) {
            int r = lrow[i];
            int b = r / RPBX;
            int dest = bglob[b] + (i - bbase[b]);
            srow[dest] = r;
            spay[dest] = lce[i];
        }
        __syncthreads();
    }
}

// Pass B (item CSR): scatter within L2-resident bucket window; slot-renumber edge data.
__global__ void k_binB0(const int* __restrict__ srow, const int2* __restrict__ spay,
                        const int* __restrict__ ofsI, int* __restrict__ curI,
                        const float* __restrict__ L0, int* __restrict__ colp,
                        int* __restrict__ eorig, int* __restrict__ inv,
                        float2* __restrict__ L0p) {
    int b = blockIdx.x;
    int r0 = b * RPB_I; if (r0 > NITEMS) r0 = NITEMS;
    int r1 = (b + 1) * RPB_I; if (r1 > NITEMS) r1 = NITEMS;
    int lo = ofsI[r0], hi = ofsI[r1];
    for (int i = lo + threadIdx.x; i < hi; i += blockDim.x) {
        int r = srow[i];
        int2 p = spay[i];  // {user, e}
        int slot = atomicAdd(&curI[r], 1);
        colp[slot] = p.x;
        eorig[slot] = p.y;
        inv[p.y] = slot;
        L0p[slot] = make_float2(L0[p.y], L0[p.y + EH]);
    }
}

// Pass B (user CSR): entries {item_global, item_slot}
__global__ void k_binB1(const int* __restrict__ srow, const int2* __restrict__ spay,
                        const int* __restrict__ ofsU, int* __restrict__ curU,
                        int2* __restrict__ csrU) {
    int b = blockIdx.x;
    int r0 = b * RPB_U; if (r0 > NUSERS) r0 = NUSERS;
    int r1 = (b + 1) * RPB_U; if (r1 > NUSERS) r1 = NUSERS;
    int lo = ofsU[r0], hi = ofsU[r1];
    for (int i = lo + threadIdx.x; i < hi; i += blockDim.x) {
        int r = srow[i];
        int2 p = spay[i];
        int slot = atomicAdd(&curU[r], 1);
        csrU[slot] = p;
    }
}

// ---------------- MFMA 64-col GEMM ----------------
// MODE 1: out[slot] = (ef[eorig[slot]]@W + b)^2, fp16 (gathered f32 A rows).
// MODE 2: out = relu(agg@W + b), fp16 (fp16 A rows); also zeroes degz[row]
//         (one lane per row) so the next layer's k_sim atomics start from 0.
// bf16 hi/lo split (3 passes) for ~2^-16 relative accuracy.
template <int MODE>
__global__ void k_gemm(const void* __restrict__ Ap, const float* __restrict__ W,
                       const float* __restrict__ bias, __half* __restrict__ out,
                       int M, const int* __restrict__ eorig, float* __restrict__ degz) {
    __shared__ float Ws[4096];
    int t = threadIdx.x;
    for (int i = t; i < 4096; i += 256) Ws[i] = W[i];
    __syncthreads();
    int lane = t & 63;
    int wid = t >> 6;
    int lr = lane & 15;
    int kg = lane >> 4;
    short8v Bh[2][4], Bl[2][4];
#pragma unroll
    for (int kt = 0; kt < 2; ++kt)
#pragma unroll
        for (int ct = 0; ct < 4; ++ct) {
            short8v bh, bl;
#pragma unroll
            for (int i = 0; i < 8; ++i) {
                int k = kt * 32 + kg * 8 + i;
                float v = Ws[k * 64 + ct * 16 + lr];
                unsigned u = __float_as_uint(v);
                float d = v - __uint_as_float(u & 0xffff0000u);
                bh[i] = (short)(u >> 16);
                bl[i] = (short)(__float_as_uint(d) >> 16);
            }
            Bh[kt][ct] = bh;
            Bl[kt][ct] = bl;
        }
    float bcol[4];
#pragma unroll
    for (int ct = 0; ct < 4; ++ct) bcol[ct] = bias[ct * 16 + lr];
    int nt = M >> 4;
    int nw = gridDim.x * 4;
    for (int tile = blockIdx.x * 4 + wid; tile < nt; tile += nw) {
        int r0 = tile << 4;
        float av[16];
        if (MODE == 1) {
            int arow = eorig[r0 + lr];
            const float* ap = &((const float*)Ap)[(size_t)arow * 64 + kg * 8];
            float4 a0 = *(const float4*)ap;
            float4 a1 = *(const float4*)(ap + 4);
            float4 a2 = *(const float4*)(ap + 32);
            float4 a3 = *(const float4*)(ap + 36);
            av[0]=a0.x; av[1]=a0.y; av[2]=a0.z; av[3]=a0.w;
            av[4]=a1.x; av[5]=a1.y; av[6]=a1.z; av[7]=a1.w;
            av[8]=a2.x; av[9]=a2.y; av[10]=a2.z; av[11]=a2.w;
            av[12]=a3.x; av[13]=a3.y; av[14]=a3.z; av[15]=a3.w;
        } else {
            const ushort* ap = &((const ushort*)Ap)[(size_t)(r0 + lr) * 64 + kg * 8];
            short8v a01 = *(const short8v*)ap;
            short8v a23 = *(const short8v*)(ap + 32);
#pragma unroll
            for (int i = 0; i < 8; ++i) {
                av[i]     = __half2float(__ushort_as_half((ushort)a01[i]));
                av[8 + i] = __half2float(__ushort_as_half((ushort)a23[i]));
            }
        }
        short8v Ah[2], Al[2];
#pragma unroll
        for (int kt = 0; kt < 2; ++kt) {
            short8v ah, al;
#pragma unroll
            for (int i = 0; i < 8; ++i) {
                float v = av[kt * 8 + i];
                unsigned u = __float_as_uint(v);
                float d = v - __uint_as_float(u & 0xffff0000u);
                ah[i] = (short)(u >> 16);
                al[i] = (short)(__float_as_uint(d) >> 16);
            }
            Ah[kt] = ah;
            Al[kt] = al;
        }
        f32x4 acc[4] = {{0, 0, 0, 0}, {0, 0, 0, 0}, {0, 0, 0, 0}, {0, 0, 0, 0}};
#pragma unroll
        for (int kt = 0; kt < 2; ++kt)
#pragma unroll
            for (int ct = 0; ct < 4; ++ct) {
                acc[ct] = __builtin_amdgcn_mfma_f32_16x16x32_bf16(Ah[kt], Bh[kt][ct], acc[ct], 0, 0, 0);
                acc[ct] = __builtin_amdgcn_mfma_f32_16x16x32_bf16(Al[kt], Bh[kt][ct], acc[ct], 0, 0, 0);
                acc[ct] = __builtin_amdgcn_mfma_f32_16x16x32_bf16(Ah[kt], Bl[kt][ct], acc[ct], 0, 0, 0);
            }
        // D layout (m89-verified): col = ct*16 + (lane&15), row = r0 + (lane>>4)*4 + r
#pragma unroll
        for (int ct = 0; ct < 4; ++ct)
#pragma unroll
            for (int r = 0; r < 4; ++r) {
                int row = r0 + kg * 4 + r;
                int col = ct * 16 + lr;
                float p = acc[ct][r] + bcol[ct];
                if (MODE == 1) {
                    out[(size_t)row * 64 + col] = __float2half(p * p);
                } else {
                    out[(size_t)row * 64 + col] = __float2half(fmaxf(p, 0.0f));
                    if (col == 0) degz[row] = 0.0f;
                }
            }
    }
}

// ---------------- per-edge similarity, item-CSR order -----------------------------
// wave per item; 8-lane groups, 8 edges/iter; 2-deep software pipeline:
// colp prefetched 2 iters ahead, cn/qp gathers 1 iter ahead (clamped indices,
// stores gated by j<je). qp loads non-temporal (stream-once, keeps xh hot in L2).
__global__ void __launch_bounds__(256) k_sim(
        const __half* __restrict__ xh, const __half* __restrict__ qp,
        const int* __restrict__ colp, const float2* __restrict__ L0p,
        const int* __restrict__ ofsI, float* __restrict__ v1p,
        float* __restrict__ v2p, float* __restrict__ deg) {
    int t = threadIdx.x;
    int wid = t >> 6, lane = t & 63, g = lane >> 3, d = lane & 7;
    int item = blockIdx.x * 4 + wid;
    if (item >= NITEMS) return;
    const ushort* xu = (const ushort*)xh;
    const ushort* qu = (const ushort*)qp;
    short8v rv = *(const short8v*)&xu[(size_t)(NUSERS + item) * 64 + d * 8];
    float rf[8];
#pragma unroll
    for (int i = 0; i < 8; ++i) rf[i] = __half2float(__ushort_as_half((ushort)rv[i]));
    int jb = ofsI[item], je = ofsI[item + 1];
    if (jb >= je) {
        if (lane == 0) deg[NUSERS + item] = 0.0f;
        return;
    }
    int last = je - 1;
    int jA = jb + g;     if (jA > last) jA = last;
    int jB = jb + 8 + g; if (jB > last) jB = last;
    int user0 = colp[jA];
    int user1 = colp[jB];
    short8v cv0 = *(const short8v*)&xu[(size_t)user0 * 64 + d * 8];
    short8v qv0 = nt_load16(&qu[(size_t)jA * 64 + d * 8]);
    float dacc = 0.0f;
    for (int j0 = jb; j0 < je; j0 += 8) {
        int jC = j0 + 16 + g; if (jC > last) jC = last;
        int jN = j0 + 8 + g;  if (jN > last) jN = last;
        int user2 = colp[jC];
        short8v cv1 = *(const short8v*)&xu[(size_t)user1 * 64 + d * 8];
        short8v qv1 = nt_load16(&qu[(size_t)jN * 64 + d * 8]);
        float aa = 0.f, bb = 0.f, ab = 0.f;
#pragma unroll
        for (int i = 0; i < 8; ++i) {
            float cf = __half2float(__ushort_as_half((ushort)cv0[i]));
            float qf = __half2float(__ushort_as_half((ushort)qv0[i]));
            float r = rf[i];
            float tr = r * qf;
            aa = fmaf(tr, r, aa);
            ab = fmaf(tr, cf, ab);
            bb = fmaf(cf * qf, cf, bb);
        }
#pragma unroll
        for (int m = 1; m < 8; m <<= 1) {
            aa += __shfl_xor(aa, m, 64);
            bb += __shfl_xor(bb, m, 64);
            ab += __shfl_xor(ab, m, 64);
        }
        int j = j0 + g;
        if (j < je && d == 0) {
            float na = fmaxf(sqrtf(aa), EPSV);
            float nb = fmaxf(sqrtf(bb), EPSV);
            float sim = fmaxf(ab / (na * nb), 0.0f);
            float2 l0 = L0p[j];
            float v1 = 0.5f * l0.x + 0.5f * sim;
            float v2 = 0.5f * l0.y + 0.5f * sim;
            v1p[j] = v1;
            v2p[j] = v2;
            atomicAdd(&deg[user0], v2);
            dacc += v1;
        }
        user0 = user1; user1 = user2; cv0 = cv1; qv0 = qv1;
    }
    dacc += __shfl_xor(dacc, 8, 64);
    dacc += __shfl_xor(dacc, 16, 64);
    dacc += __shfl_xor(dacc, 32, 64);
    if (lane == 0) deg[NUSERS + item] = dacc;  // exclusive: plain store
}

// ---------------- aggregation (rsqrt on the fly, 8-wide broadcast unroll) ---------
#define IBLK 3750
__global__ void __launch_bounds__(256) k_agg(
        const int* __restrict__ ofsI, const int* __restrict__ colp,
        const float* __restrict__ v1p, const int* __restrict__ ofsU,
        const int2* __restrict__ csrU, const float* __restrict__ v2p,
        const float* __restrict__ deg, const __half* __restrict__ xh,
        __half* __restrict__ agg) {
    int t = threadIdx.x;
    int half_id = t >> 5, sl = t & 31;
    const __half2* h2 = (const __half2*)xh;
    float2 acc = make_float2(0.0f, 0.0f);
    int node, jb, je;
    bool isItem = blockIdx.x < IBLK;
    if (isItem) {
        int il = blockIdx.x * 8 + half_id;  // 0..29999
        node = NUSERS + il;
        jb = ofsI[il]; je = ofsI[il + 1];
    } else {
        int ul = (blockIdx.x - IBLK) * 8 + half_id;  // 0..59999
        node = ul;
        jb = ofsU[ul]; je = ofsU[ul + 1];
    }
    float dgn = deg[node];
    float dn = dgn > 0.0f ? rsqrtf(dgn) : 0.0f;
    for (int j0 = jb; j0 < je; j0 += 32) {
        int cnt = je - j0;
        if (cnt > 32) cnt = 32;
        int col = 0;
        float wgt = 0.0f;
        if (sl < cnt) {
            if (isItem) {
                col = colp[j0 + sl];
                wgt = dn * v1p[j0 + sl];
            } else {
                int2 ce = csrU[j0 + sl];
                col = ce.x;
                wgt = dn * v2p[ce.y];
            }
            float dc = deg[col];
            wgt *= (dc > 0.0f ? rsqrtf(dc) : 0.0f);
        }
        int u = 0;
        for (; u + 8 <= cnt; u += 8) {
            int c0 = __shfl(col, u, 32);
            int c1 = __shfl(col, u + 1, 32);
            int c2 = __shfl(col, u + 2, 32);
            int c3 = __shfl(col, u + 3, 32);
            int c4 = __shfl(col, u + 4, 32);
            int c5 = __shfl(col, u + 5, 32);
            int c6 = __shfl(col, u + 6, 32);
            int c7 = __shfl(col, u + 7, 32);
            float w0 = __shfl(wgt, u, 32);
            float w1 = __shfl(wgt, u + 1, 32);
            float w2 = __shfl(wgt, u + 2, 32);
            float w3 = __shfl(wgt, u + 3, 32);
            float w4 = __shfl(wgt, u + 4, 32);
            float w5 = __shfl(wgt, u + 5, 32);
            float w6 = __shfl(wgt, u + 6, 32);
            float w7 = __shfl(wgt, u + 7, 32);
            float2 h0 = __half22float2(h2[(size_t)c0 * 32 + sl]);
            float2 h1 = __half22float2(h2[(size_t)c1 * 32 + sl]);
            float2 h2v = __half22float2(h2[(size_t)c2 * 32 + sl]);
            float2 h3 = __half22float2(h2[(size_t)c3 * 32 + sl]);
            float2 h4 = __half22float2(h2[(size_t)c4 * 32 + sl]);
            float2 h5 = __half22float2(h2[(size_t)c5 * 32 + sl]);
            float2 h6 = __half22float2(h2[(size_t)c6 * 32 + sl]);
            float2 h7 = __half22float2(h2[(size_t)c7 * 32 + sl]);
            acc.x = fmaf(w0, h0.x, acc.x);  acc.y = fmaf(w0, h0.y, acc.y);
            acc.x = fmaf(w1, h1.x, acc.x);  acc.y = fmaf(w1, h1.y, acc.y);
            acc.x = fmaf(w2, h2v.x, acc.x); acc.y = fmaf(w2, h2v.y, acc.y);
            acc.x = fmaf(w3, h3.x, acc.x);  acc.y = fmaf(w3, h3.y, acc.y);
            acc.x = fmaf(w4, h4.x, acc.x);  acc.y = fmaf(w4, h4.y, acc.y);
            acc.x = fmaf(w5, h5.x, acc.x);  acc.y = fmaf(w5, h5.y, acc.y);
            acc.x = fmaf(w6, h6.x, acc.x);  acc.y = fmaf(w6, h6.y, acc.y);
            acc.x = fmaf(w7, h7.x, acc.x);  acc.y = fmaf(w7, h7.y, acc.y);
        }
        for (; u + 4 <= cnt; u += 4) {
            int c0 = __shfl(col, u, 32);
            int c1 = __shfl(col, u + 1, 32);
            int c2 = __shfl(col, u + 2, 32);
            int c3 = __shfl(col, u + 3, 32);
            float w0 = __shfl(wgt, u, 32);
            float w1 = __shfl(wgt, u + 1, 32);
            float w2 = __shfl(wgt, u + 2, 32);
            float w3 = __shfl(wgt, u + 3, 32);
            float2 h0 = __half22float2(h2[(size_t)c0 * 32 + sl]);
            float2 h1 = __half22float2(h2[(size_t)c1 * 32 + sl]);
            float2 h2v = __half22float2(h2[(size_t)c2 * 32 + sl]);
            float2 h3 = __half22float2(h2[(size_t)c3 * 32 + sl]);
            acc.x = fmaf(w0, h0.x, acc.x);  acc.y = fmaf(w0, h0.y, acc.y);
            acc.x = fmaf(w1, h1.x, acc.x);  acc.y = fmaf(w1, h1.y, acc.y);
            acc.x = fmaf(w2, h2v.x, acc.x); acc.y = fmaf(w2, h2v.y, acc.y);
            acc.x = fmaf(w3, h3.x, acc.x);  acc.y = fmaf(w3, h3.y, acc.y);
        }
        for (; u < cnt; ++u) {
            int c = __shfl(col, u, 32);
            float wv = __shfl(wgt, u, 32);
            float2 hv = __half22float2(h2[(size_t)c * 32 + sl]);
            acc.x = fmaf(wv, hv.x, acc.x);
            acc.y = fmaf(wv, hv.y, acc.y);
        }
    }
    ((__half2*)agg)[(size_t)node * 32 + sl] = __floats2half2_rn(acc.x, acc.y);
}

// ---------------- final batched dot ----------------
__global__ void k_final(const __half* __restrict__ xh, const int* __restrict__ uidx,
                        const int* __restrict__ iidx, const float* __restrict__ Bu,
                        const float* __restrict__ Bi, const float* __restrict__ Mu,
                        float* __restrict__ out) {
    int t = threadIdx.x;
    int le = t >> 4, kq = t & 15, k0 = kq * 4;
    int i = blockIdx.x * 16 + le;
    if (i >= NBATCH) return;
    int u = uidx[i], it = iidx[i];
    float4 a = h4_to_f4(&xh[(size_t)u * 64 + k0]);
    float4 b = h4_to_f4(&xh[(size_t)(NUSERS + it) * 64 + k0]);
    float d = a.x * b.x + a.y * b.y + a.z * b.z + a.w * b.w;
#pragma unroll
    for (int m = 1; m < 16; m <<= 1) d += __shfl_xor(d, m, 64);
    if (kq == 0) out[i] = d + Bu[u] + Bi[it] + Mu[0];
}

extern "C" void kernel_launch(void* const* d_in, const int* in_sizes, int n_in,
                              void* d_out, int out_size, void* d_ws, size_t ws_size,
                              hipStream_t stream) {
    const float* Gu    = (const float*)d_in[0];
    const float* Gi    = (const float*)d_in[1];
    const float* Bu    = (const float*)d_in[2];
    const float* Bi    = (const float*)d_in[3];
    const float* Mu    = (const float*)d_in[4];
    const float* projW = (const float*)d_in[5];
    const float* projb = (const float*)d_in[6];
    const float* gcnW  = (const float*)d_in[7];
    const float* gcnb  = (const float*)d_in[8];
    const float* ef    = (const float*)d_in[9];
    const float* L0    = (const float*)d_in[10];
    const int*   erow  = (const int*)d_in[11];
    const int*   ecol  = (const int*)d_in[12];
    const int*   uidx  = (const int*)d_in[13];
    const int*   iidx  = (const int*)d_in[14];
    float* out = (float*)d_out;

    char* w = (char*)d_ws;
    size_t off = 0;
    auto take = [&](size_t bytes) -> void* {
        void* p = w + off;
        off += (bytes + 255) & ~(size_t)255;
        return p;
    };
    __half* xh    = (__half*)take((size_t)NNODES * KDIM * 2);
    __half* agg   = (__half*)take((size_t)NNODES * KDIM * 2);
    float*  v1p   = (float*)take((size_t)EH * 4);
    float*  v2p   = (float*)take((size_t)EH * 4);
    float*  deg   = (float*)take((size_t)NNODES * 4);
    int*    cntI  = (int*)take((size_t)NPAD_I * 4);   // adjacent with cntU: one zero pass
    int*    cntU  = (int*)take((size_t)NPAD_U * 4);
    int*    ofsI  = (int*)take((size_t)(NITEMS + 1) * 4);
    int*    curI  = (int*)take((size_t)(NITEMS + 1) * 4);
    int*    ofsU  = (int*)take((size_t)(NUSERS + 1) * 4);
    int*    curU  = (int*)take((size_t)(NUSERS + 1) * 4);
    int*    gcurI = (int*)take((size_t)NB * 4);
    int*    gcurU = (int*)take((size_t)NB * 4);
    int*    colp  = (int*)take((size_t)EH * 4);
    int*    eorig = (int*)take((size_t)EH * 4);
    int*    inv   = (int*)take((size_t)EH * 4);
    float2* L0p   = (float2*)take((size_t)EH * 8);
    int2*   csrU  = (int2*)take((size_t)EH * 8);
    __half* qp    = (__half*)take((size_t)EH * KDIM * 2);
    // CSR-build staging aliases qp (qp written only after both builds)
    int*  srow = (int*)qp;
    int2* spay = (int2*)((char*)qp + (size_t)EH * 4);

    // ---- init: zero cnt/deg, xh = fp16(concat(Gu,Gi)) ----
    k_init<<<(NNODES * KDIM / 4 + 255) / 256, 256, 0, stream>>>(Gu, Gi, xh, cntI, deg);

    // ---- CSR builds (layer-invariant) ----
    k_count2<<<(EH + 255) / 256, 256, 0, stream>>>(erow, ecol, cntI, cntU);
    k_scan2<<<2, 1024, 0, stream>>>(cntI, ofsI, curI, cntU, ofsU, curU, gcurI, gcurU);
    k_binA<0, RPB_I><<<256, 256, 0, stream>>>(erow, ecol, nullptr, gcurI, srow, spay);
    k_binB0<<<NB, 512, 0, stream>>>(srow, spay, ofsI, curI, L0, colp, eorig, inv, L0p);
    k_binA<1, RPB_U><<<256, 256, 0, stream>>>(erow, ecol, inv, gcurU, srow, spay);
    k_binB1<<<NB, 512, 0, stream>>>(srow, spay, ofsU, curU, csrU);

    // qp[slot] = (ef[eorig[slot]] @ projW + projb)^2, fp16 (overwrites staging)
    k_gemm<1><<<1024, 256, 0, stream>>>(ef, projW, projb, qp, EH, eorig, nullptr);

    for (int l = 0; l < 3; ++l) {
        k_sim<<<(NITEMS + 3) / 4, 256, 0, stream>>>(xh, qp, colp, L0p, ofsI, v1p, v2p, deg);
        k_agg<<<IBLK + NUSERS / 8, 256, 0, stream>>>(ofsI, colp, v1p, ofsU, csrU, v2p,
                                                     deg, xh, agg);
        k_gemm<2><<<512, 256, 0, stream>>>(agg, gcnW + (size_t)l * 4096,
                                           gcnb + (size_t)l * 64, xh, NNODES, nullptr, deg);
    }
    k_final<<<(NBATCH + 15) / 16, 256, 0, stream>>>(xh, uidx, iidx, Bu, Bi, Mu, out);
}

// Round 12
// 733.803 us; speedup vs baseline: 1.0373x; 1.0373x over previous
//
#include <hip/hip_runtime.h>
#include <hip/hip_fp16.h>

#define NUSERS 60000
#define NITEMS 30000
#define NNODES 90000
#define KDIM 64
#define EH 1000000
#define E2 2000000
#define NBATCH 100000
#define EPSV 1e-8f

#define NB 128      // coarse buckets for CSR builds
#define RPB_I 240   // 128*240 = 30720 >= NITEMS
#define RPB_U 472   // 128*472 = 60416 >= NUSERS
#define CHUNK 2048  // edges per block-round in binA2
#define NPAD_I 32768
#define NPAD_U 61440

typedef __attribute__((ext_vector_type(8))) short short8v;
typedef __attribute__((ext_vector_type(4))) float f32x4;

__device__ inline float4 h4_to_f4(const __half* p) {
    float2 raw = *(const float2*)p;  // single 8B load
    __half2 a = *(__half2*)&raw.x;
    __half2 b = *(__half2*)&raw.y;
    float2 fa = __half22float2(a), fb = __half22float2(b);
    return make_float4(fa.x, fa.y, fb.x, fb.y);
}

// ---------------- init: zero cnt/deg + xh = fp16(concat(Gu,Gi)) ----------------
__global__ void k_init(const float* __restrict__ Gu, const float* __restrict__ Gi,
                       __half* __restrict__ xh, int* __restrict__ cnt,
                       float* __restrict__ deg) {
    int i = blockIdx.x * 256 + threadIdx.x;
    if (i < NPAD_I + NPAD_U) cnt[i] = 0;
    if (i < NNODES) deg[i] = 0.0f;
    int idx = i * 4;
    if (idx >= NNODES * KDIM) return;
    const float* src = idx < NUSERS * KDIM ? &Gu[idx] : &Gi[idx - NUSERS * KDIM];
    float4 v = *(const float4*)src;
    ((__half2*)xh)[idx / 2]     = __floats2half2_rn(v.x, v.y);
    ((__half2*)xh)[idx / 2 + 1] = __floats2half2_rn(v.z, v.w);
}

// ---------------- CSR builds ----------------
__global__ void k_count2(const int* __restrict__ erow, const int* __restrict__ ecol,
                         int* __restrict__ cntI, int* __restrict__ cntU) {
    int e = blockIdx.x * 256 + threadIdx.x;
    if (e < EH) {
        atomicAdd(&cntI[erow[e] - NUSERS], 1);
        atomicAdd(&cntU[ecol[e]], 1);
    }
}

// grid=2: block 0 scans item counts, block 1 user counts; each block also writes
// its bucket cursors (gcur) from its own offsets.
__global__ void k_scan2(const int* __restrict__ cntI, int* __restrict__ ofsI,
                        int* __restrict__ curI, const int* __restrict__ cntU,
                        int* __restrict__ ofsU, int* __restrict__ curU,
                        int* __restrict__ gcurI, int* __restrict__ gcurU) {
    const int* counts; int* offsets; int* cursor; int n;
    if (blockIdx.x == 0) { counts = cntI; offsets = ofsI; cursor = curI; n = NITEMS; }
    else                 { counts = cntU; offsets = ofsU; cursor = curU; n = NUSERS; }
    __shared__ int wsum[17];
    int t = threadIdx.x;
    int lane = t & 63, wid = t >> 6;
    int carry = 0;
    int npad = (n + 4095) & ~4095;
    for (int base = 0; base < npad; base += 4096) {
        int i0 = base + t * 4;
        int4 v = *(const int4*)&counts[i0];  // padded+zeroed, safe
        int s0 = v.x, s1 = s0 + v.y, s2 = s1 + v.z, s3 = s2 + v.w;
        int ws = s3;
#pragma unroll
        for (int o = 1; o < 64; o <<= 1) {
            int u = __shfl_up(ws, o, 64);
            if (lane >= o) ws += u;
        }
        if (lane == 63) wsum[wid] = ws;
        __syncthreads();
        if (wid == 0) {
            int wv = (lane < 16) ? wsum[lane] : 0;
#pragma unroll
            for (int o = 1; o < 16; o <<= 1) {
                int u = __shfl_up(wv, o, 64);
                if (lane >= o) wv += u;
            }
            if (lane < 16) wsum[lane] = wv;
            if (lane == 15) wsum[16] = wv;
        }
        __syncthreads();
        int wbase = (wid > 0) ? wsum[wid - 1] : 0;
        int texcl = carry + wbase + (ws - s3);
        if (i0 < n)     { offsets[i0]     = texcl;      cursor[i0]     = texcl; }
        if (i0 + 1 < n) { offsets[i0 + 1] = texcl + s0; cursor[i0 + 1] = texcl + s0; }
        if (i0 + 2 < n) { offsets[i0 + 2] = texcl + s1; cursor[i0 + 2] = texcl + s1; }
        if (i0 + 3 < n) { offsets[i0 + 3] = texcl + s2; cursor[i0 + 3] = texcl + s2; }
        carry += wsum[16];
        __syncthreads();
    }
    if (t == 0) offsets[n] = carry;
    __syncthreads();
    if (blockIdx.x == 0) {
        if (t < NB) {
            int r = t * RPB_I; if (r > NITEMS) r = NITEMS;
            gcurI[t] = ofsI[r];
        }
    } else {
        if (t < NB) {
            int r = t * RPB_U; if (r > NUSERS) r = NUSERS;
            gcurU[t] = ofsU[r];
        }
    }
}

// Fused Pass A: ONE edge-read pass; two LDS counting-sort phases per chunk.
// Phase A (item key): staging payload {user, e}
// Phase B (user key): staging payload {item_global, e}  (inv looked up in binB1)
__global__ void k_binA2(const int* __restrict__ erow, const int* __restrict__ ecol,
                        int* __restrict__ gcurI, int* __restrict__ gcurU,
                        int* __restrict__ srowI, int2* __restrict__ spayI,
                        int* __restrict__ srowU, int2* __restrict__ spayU) {
    __shared__ int bcnt[NB];
    __shared__ int bbase[NB];
    __shared__ int bpos[NB];
    __shared__ int bglob[NB];
    __shared__ int wtot[2];
    __shared__ int lrow[CHUNK];
    __shared__ int2 lce[CHUNK];
    int t = threadIdx.x;
    for (int base = blockIdx.x * CHUNK; base < EH; base += gridDim.x * CHUNK) {
        int mr[8], mu[8];
#pragma unroll
        for (int k = 0; k < 8; ++k) {
            int e = base + k * 256 + t;
            if (e < EH) { mr[k] = erow[e] - NUSERS; mu[k] = ecol[e]; }
            else        { mr[k] = -1; mu[k] = 0; }
        }
        // ---------- phase A: key = item row ----------
        for (int i = t; i < NB; i += 256) bcnt[i] = 0;
        __syncthreads();
        int mbA[8];
#pragma unroll
        for (int k = 0; k < 8; ++k) {
            mbA[k] = (mr[k] >= 0) ? mr[k] / RPB_I : -1;
            if (mbA[k] >= 0) atomicAdd(&bcnt[mbA[k]], 1);
        }
        __syncthreads();
        if (t < NB) {
            int v = bcnt[t];
            int s = v;
#pragma unroll
            for (int o = 1; o < 64; o <<= 1) {
                int u = __shfl_up(s, o, 64);
                if ((t & 63) >= o) s += u;
            }
            bbase[t] = s - v;
            if ((t & 63) == 63) wtot[t >> 6] = s;
        }
        __syncthreads();
        if (t >= 64 && t < NB) bbase[t] += wtot[0];
        if (t < NB) bpos[t] = 0;
        __syncthreads();
#pragma unroll
        for (int k = 0; k < 8; ++k) {
            if (mbA[k] >= 0) {
                int p = bbase[mbA[k]] + atomicAdd(&bpos[mbA[k]], 1);
                lrow[p] = mr[k];
                lce[p] = make_int2(mu[k], base + k * 256 + t);
            }
        }
        __syncthreads();
        if (t < NB) bglob[t] = bcnt[t] ? atomicAdd(&gcurI[t], bcnt[t]) : 0;
        __syncthreads();
        {
            int total = bbase[NB - 1] + bcnt[NB - 1];
            for (int i = t; i < total; i += 256) {
                int r = lrow[i];
                int b = r / RPB_I;
                int dest = bglob[b] + (i - bbase[b]);
                srowI[dest] = r;
                spayI[dest] = lce[i];
            }
        }
        __syncthreads();
        // ---------- phase B: key = user ----------
        for (int i = t; i < NB; i += 256) bcnt[i] = 0;
        __syncthreads();
        int mbB[8];
#pragma unroll
        for (int k = 0; k < 8; ++k) {
            mbB[k] = (mr[k] >= 0) ? mu[k] / RPB_U : -1;
            if (mbB[k] >= 0) atomicAdd(&bcnt[mbB[k]], 1);
        }
        __syncthreads();
        if (t < NB) {
            int v = bcnt[t];
            int s = v;
#pragma unroll
            for (int o = 1; o < 64; o <<= 1) {
                int u = __shfl_up(s, o, 64);
                if ((t & 63) >= o) s += u;
            }
            bbase[t] = s - v;
            if ((t & 63) == 63) wtot[t >> 6] = s;
        }
        __syncthreads();
        if (t >= 64 && t < NB) bbase[t] += wtot[0];
        if (t < NB) bpos[t] = 0;
        __syncthreads();
#pragma unroll
        for (int k = 0; k < 8; ++k) {
            if (mbB[k] >= 0) {
                int p = bbase[mbB[k]] + atomicAdd(&bpos[mbB[k]], 1);
                lrow[p] = mu[k];
                lce[p] = make_int2(mr[k] + NUSERS, base + k * 256 + t);
            }
        }
        __syncthreads();
        if (t < NB) bglob[t] = bcnt[t] ? atomicAdd(&gcurU[t], bcnt[t]) : 0;
        __syncthreads();
        {
            int total = bbase[NB - 1] + bcnt[NB - 1];
            for (int i = t; i < total; i += 256) {
                int r = lrow[i];
                int b = r / RPB_U;
                int dest = bglob[b] + (i - bbase[b]);
                srowU[dest] = r;
                spayU[dest] = lce[i];
            }
        }
        __syncthreads();
    }
}

// Pass B (item CSR): scatter within L2-resident bucket window; slot-renumber edge data.
__global__ void k_binB0(const int* __restrict__ srow, const int2* __restrict__ spay,
                        const int* __restrict__ ofsI, int* __restrict__ curI,
                        const float* __restrict__ L0, int* __restrict__ colp,
                        int* __restrict__ eorig, int* __restrict__ inv,
                        float2* __restrict__ L0p) {
    int b = blockIdx.x;
    int r0 = b * RPB_I; if (r0 > NITEMS) r0 = NITEMS;
    int r1 = (b + 1) * RPB_I; if (r1 > NITEMS) r1 = NITEMS;
    int lo = ofsI[r0], hi = ofsI[r1];
    for (int i = lo + threadIdx.x; i < hi; i += blockDim.x) {
        int r = srow[i];
        int2 p = spay[i];  // {user, e}
        int slot = atomicAdd(&curI[r], 1);
        colp[slot] = p.x;
        eorig[slot] = p.y;
        inv[p.y] = slot;
        L0p[slot] = make_float2(L0[p.y], L0[p.y + EH]);
    }
}

// Pass B (user CSR): staging {item_global, e} -> csrU entries {item_global, inv[e]}
__global__ void k_binB1(const int* __restrict__ srow, const int2* __restrict__ spay,
                        const int* __restrict__ ofsU, int* __restrict__ curU,
                        const int* __restrict__ inv, int2* __restrict__ csrU) {
    int b = blockIdx.x;
    int r0 = b * RPB_U; if (r0 > NUSERS) r0 = NUSERS;
    int r1 = (b + 1) * RPB_U; if (r1 > NUSERS) r1 = NUSERS;
    int lo = ofsU[r0], hi = ofsU[r1];
    for (int i = lo + threadIdx.x; i < hi; i += blockDim.x) {
        int r = srow[i];
        int2 p = spay[i];
        int slot = atomicAdd(&curU[r], 1);
        csrU[slot] = make_int2(p.x, inv[p.y]);
    }
}

// ---------------- MFMA 64-col GEMM ----------------
// MODE 1: out[slot] = (ef[eorig[slot]]@W + b)^2, fp16 (gathered f32 A rows).
// MODE 2: out = relu(agg@W + b), fp16 (fp16 A rows); also zeroes degz[row]
//         (one lane per row) so the next layer's k_sim atomics start from 0.
// bf16 hi/lo split (3 passes) for ~2^-16 relative accuracy.
template <int MODE>
__global__ void k_gemm(const void* __restrict__ Ap, const float* __restrict__ W,
                       const float* __restrict__ bias, __half* __restrict__ out,
                       int M, const int* __restrict__ eorig, float* __restrict__ degz) {
    __shared__ float Ws[4096];
    int t = threadIdx.x;
    for (int i = t; i < 4096; i += 256) Ws[i] = W[i];
    __syncthreads();
    int lane = t & 63;
    int wid = t >> 6;
    int lr = lane & 15;
    int kg = lane >> 4;
    short8v Bh[2][4], Bl[2][4];
#pragma unroll
    for (int kt = 0; kt < 2; ++kt)
#pragma unroll
        for (int ct = 0; ct < 4; ++ct) {
            short8v bh, bl;
#pragma unroll
            for (int i = 0; i < 8; ++i) {
                int k = kt * 32 + kg * 8 + i;
                float v = Ws[k * 64 + ct * 16 + lr];
                unsigned u = __float_as_uint(v);
                float d = v - __uint_as_float(u & 0xffff0000u);
                bh[i] = (short)(u >> 16);
                bl[i] = (short)(__float_as_uint(d) >> 16);
            }
            Bh[kt][ct] = bh;
            Bl[kt][ct] = bl;
        }
    float bcol[4];
#pragma unroll
    for (int ct = 0; ct < 4; ++ct) bcol[ct] = bias[ct * 16 + lr];
    int nt = M >> 4;
    int nw = gridDim.x * 4;
    for (int tile = blockIdx.x * 4 + wid; tile < nt; tile += nw) {
        int r0 = tile << 4;
        float av[16];
        if (MODE == 1) {
            int arow = eorig[r0 + lr];
            const float* ap = &((const float*)Ap)[(size_t)arow * 64 + kg * 8];
            float4 a0 = *(const float4*)ap;
            float4 a1 = *(const float4*)(ap + 4);
            float4 a2 = *(const float4*)(ap + 32);
            float4 a3 = *(const float4*)(ap + 36);
            av[0]=a0.x; av[1]=a0.y; av[2]=a0.z; av[3]=a0.w;
            av[4]=a1.x; av[5]=a1.y; av[6]=a1.z; av[7]=a1.w;
            av[8]=a2.x; av[9]=a2.y; av[10]=a2.z; av[11]=a2.w;
            av[12]=a3.x; av[13]=a3.y; av[14]=a3.z; av[15]=a3.w;
        } else {
            const ushort* ap = &((const ushort*)Ap)[(size_t)(r0 + lr) * 64 + kg * 8];
            short8v a01 = *(const short8v*)ap;
            short8v a23 = *(const short8v*)(ap + 32);
#pragma unroll
            for (int i = 0; i < 8; ++i) {
                av[i]     = __half2float(__ushort_as_half((ushort)a01[i]));
                av[8 + i] = __half2float(__ushort_as_half((ushort)a23[i]));
            }
        }
        short8v Ah[2], Al[2];
#pragma unroll
        for (int kt = 0; kt < 2; ++kt) {
            short8v ah, al;
#pragma unroll
            for (int i = 0; i < 8; ++i) {
                float v = av[kt * 8 + i];
                unsigned u = __float_as_uint(v);
                float d = v - __uint_as_float(u & 0xffff0000u);
                ah[i] = (short)(u >> 16);
                al[i] = (short)(__float_as_uint(d) >> 16);
            }
            Ah[kt] = ah;
            Al[kt] = al;
        }
        f32x4 acc[4] = {{0, 0, 0, 0}, {0, 0, 0, 0}, {0, 0, 0, 0}, {0, 0, 0, 0}};
#pragma unroll
        for (int kt = 0; kt < 2; ++kt)
#pragma unroll
            for (int ct = 0; ct < 4; ++ct) {
                acc[ct] = __builtin_amdgcn_mfma_f32_16x16x32_bf16(Ah[kt], Bh[kt][ct], acc[ct], 0, 0, 0);
                acc[ct] = __builtin_amdgcn_mfma_f32_16x16x32_bf16(Al[kt], Bh[kt][ct], acc[ct], 0, 0, 0);
                acc[ct] = __builtin_amdgcn_mfma_f32_16x16x32_bf16(Ah[kt], Bl[kt][ct], acc[ct], 0, 0, 0);
            }
        // D layout (m89-verified): col = ct*16 + (lane&15), row = r0 + (lane>>4)*4 + r
#pragma unroll
        for (int ct = 0; ct < 4; ++ct)
#pragma unroll
            for (int r = 0; r < 4; ++r) {
                int row = r0 + kg * 4 + r;
                int col = ct * 16 + lr;
                float p = acc[ct][r] + bcol[ct];
                if (MODE == 1) {
                    out[(size_t)row * 64 + col] = __float2half(p * p);
                } else {
                    out[(size_t)row * 64 + col] = __float2half(fmaxf(p, 0.0f));
                    if (col == 0) degz[row] = 0.0f;
                }
            }
    }
}

// ---------------- per-edge similarity, item-CSR order (round-10 structure) --------
// wave per item; 8-lane groups -> 8 edges/iteration; rn register-resident.
__global__ void __launch_bounds__(256) k_sim(
        const __half* __restrict__ xh, const __half* __restrict__ qp,
        const int* __restrict__ colp, const float2* __restrict__ L0p,
        const int* __restrict__ ofsI, float* __restrict__ v1p,
        float* __restrict__ v2p, float* __restrict__ deg) {
    int t = threadIdx.x;
    int wid = t >> 6, lane = t & 63, g = lane >> 3, d = lane & 7;
    int item = blockIdx.x * 4 + wid;
    if (item >= NITEMS) return;
    const ushort* xu = (const ushort*)xh;
    const ushort* qu = (const ushort*)qp;
    short8v rv = *(const short8v*)&xu[(size_t)(NUSERS + item) * 64 + d * 8];
    float rf[8];
#pragma unroll
    for (int i = 0; i < 8; ++i) rf[i] = __half2float(__ushort_as_half((ushort)rv[i]));
    int jb = ofsI[item], je = ofsI[item + 1];
    float dacc = 0.0f;
    for (int j0 = jb; j0 < je; j0 += 8) {
        int j = j0 + g;
        bool act = j < je;
        float aa = 0.f, bb = 0.f, ab = 0.f;
        int user = 0;
        if (act) {
            user = colp[j];
            short8v cv = *(const short8v*)&xu[(size_t)user * 64 + d * 8];
            short8v qv = *(const short8v*)&qu[(size_t)j * 64 + d * 8];
#pragma unroll
            for (int i = 0; i < 8; ++i) {
                float cf = __half2float(__ushort_as_half((ushort)cv[i]));
                float qf = __half2float(__ushort_as_half((ushort)qv[i]));
                float r = rf[i];
                float tr = r * qf;
                aa = fmaf(tr, r, aa);
                ab = fmaf(tr, cf, ab);
                bb = fmaf(cf * qf, cf, bb);
            }
        }
#pragma unroll
        for (int m = 1; m < 8; m <<= 1) {
            aa += __shfl_xor(aa, m, 64);
            bb += __shfl_xor(bb, m, 64);
            ab += __shfl_xor(ab, m, 64);
        }
        if (act && d == 0) {
            float na = fmaxf(sqrtf(aa), EPSV);
            float nb = fmaxf(sqrtf(bb), EPSV);
            float sim = fmaxf(ab / (na * nb), 0.0f);
            float2 l0 = L0p[j];
            float v1 = 0.5f * l0.x + 0.5f * sim;
            float v2 = 0.5f * l0.y + 0.5f * sim;
            v1p[j] = v1;
            v2p[j] = v2;
            atomicAdd(&deg[user], v2);
            dacc += v1;
        }
    }
    dacc += __shfl_xor(dacc, 8, 64);
    dacc += __shfl_xor(dacc, 16, 64);
    dacc += __shfl_xor(dacc, 32, 64);
    if (lane == 0) deg[NUSERS + item] = dacc;  // exclusive: plain store
}

// ---------------- aggregation (rsqrt on the fly, 8-wide broadcast unroll) ---------
#define IBLK 3750
__global__ void __launch_bounds__(256) k_agg(
        const int* __restrict__ ofsI, const int* __restrict__ colp,
        const float* __restrict__ v1p, const int* __restrict__ ofsU,
        const int2* __restrict__ csrU, const float* __restrict__ v2p,
        const float* __restrict__ deg, const __half* __restrict__ xh,
        __half* __restrict__ agg) {
    int t = threadIdx.x;
    int half_id = t >> 5, sl = t & 31;
    const __half2* h2 = (const __half2*)xh;
    float2 acc = make_float2(0.0f, 0.0f);
    int node, jb, je;
    bool isItem = blockIdx.x < IBLK;
    if (isItem) {
        int il = blockIdx.x * 8 + half_id;  // 0..29999
        node = NUSERS + il;
        jb = ofsI[il]; je = ofsI[il + 1];
    } else {
        int ul = (blockIdx.x - IBLK) * 8 + half_id;  // 0..59999
        node = ul;
        jb = ofsU[ul]; je = ofsU[ul + 1];
    }
    float dgn = deg[node];
    float dn = dgn > 0.0f ? rsqrtf(dgn) : 0.0f;
    for (int j0 = jb; j0 < je; j0 += 32) {
        int cnt = je - j0;
        if (cnt > 32) cnt = 32;
        int col = 0;
        float wgt = 0.0f;
        if (sl < cnt) {
            if (isItem) {
                col = colp[j0 + sl];
                wgt = dn * v1p[j0 + sl];
            } else {
                int2 ce = csrU[j0 + sl];
                col = ce.x;
                wgt = dn * v2p[ce.y];
            }
            float dc = deg[col];
            wgt *= (dc > 0.0f ? rsqrtf(dc) : 0.0f);
        }
        int u = 0;
        for (; u + 8 <= cnt; u += 8) {
            int c0 = __shfl(col, u, 32);
            int c1 = __shfl(col, u + 1, 32);
            int c2 = __shfl(col, u + 2, 32);
            int c3 = __shfl(col, u + 3, 32);
            int c4 = __shfl(col, u + 4, 32);
            int c5 = __shfl(col, u + 5, 32);
            int c6 = __shfl(col, u + 6, 32);
            int c7 = __shfl(col, u + 7, 32);
            float w0 = __shfl(wgt, u, 32);
            float w1 = __shfl(wgt, u + 1, 32);
            float w2 = __shfl(wgt, u + 2, 32);
            float w3 = __shfl(wgt, u + 3, 32);
            float w4 = __shfl(wgt, u + 4, 32);
            float w5 = __shfl(wgt, u + 5, 32);
            float w6 = __shfl(wgt, u + 6, 32);
            float w7 = __shfl(wgt, u + 7, 32);
            float2 h0 = __half22float2(h2[(size_t)c0 * 32 + sl]);
            float2 h1 = __half22float2(h2[(size_t)c1 * 32 + sl]);
            float2 h2v = __half22float2(h2[(size_t)c2 * 32 + sl]);
            float2 h3 = __half22float2(h2[(size_t)c3 * 32 + sl]);
            float2 h4 = __half22float2(h2[(size_t)c4 * 32 + sl]);
            float2 h5 = __half22float2(h2[(size_t)c5 * 32 + sl]);
            float2 h6 = __half22float2(h2[(size_t)c6 * 32 + sl]);
            float2 h7 = __half22float2(h2[(size_t)c7 * 32 + sl]);
            acc.x = fmaf(w0, h0.x, acc.x);  acc.y = fmaf(w0, h0.y, acc.y);
            acc.x = fmaf(w1, h1.x, acc.x);  acc.y = fmaf(w1, h1.y, acc.y);
            acc.x = fmaf(w2, h2v.x, acc.x); acc.y = fmaf(w2, h2v.y, acc.y);
            acc.x = fmaf(w3, h3.x, acc.x);  acc.y = fmaf(w3, h3.y, acc.y);
            acc.x = fmaf(w4, h4.x, acc.x);  acc.y = fmaf(w4, h4.y, acc.y);
            acc.x = fmaf(w5, h5.x, acc.x);  acc.y = fmaf(w5, h5.y, acc.y);
            acc.x = fmaf(w6, h6.x, acc.x);  acc.y = fmaf(w6, h6.y, acc.y);
            acc.x = fmaf(w7, h7.x, acc.x);  acc.y = fmaf(w7, h7.y, acc.y);
        }
        for (; u + 4 <= cnt; u += 4) {
            int c0 = __shfl(col, u, 32);
            int c1 = __shfl(col, u + 1, 32);
            int c2 = __shfl(col, u + 2, 32);
            int c3 = __shfl(col, u + 3, 32);
            float w0 = __shfl(wgt, u, 32);
            float w1 = __shfl(wgt, u + 1, 32);
            float w2 = __shfl(wgt, u + 2, 32);
            float w3 = __shfl(wgt, u + 3, 32);
            float2 h0 = __half22float2(h2[(size_t)c0 * 32 + sl]);
            float2 h1 = __half22float2(h2[(size_t)c1 * 32 + sl]);
            float2 h2v = __half22float2(h2[(size_t)c2 * 32 + sl]);
            float2 h3 = __half22float2(h2[(size_t)c3 * 32 + sl]);
            acc.x = fmaf(w0, h0.x, acc.x);  acc.y = fmaf(w0, h0.y, acc.y);
            acc.x = fmaf(w1, h1.x, acc.x);  acc.y = fmaf(w1, h1.y, acc.y);
            acc.x = fmaf(w2, h2v.x, acc.x); acc.y = fmaf(w2, h2v.y, acc.y);
            acc.x = fmaf(w3, h3.x, acc.x);  acc.y = fmaf(w3, h3.y, acc.y);
        }
        for (; u < cnt; ++u) {
            int c = __shfl(col, u, 32);
            float wv = __shfl(wgt, u, 32);
            float2 hv = __half22float2(h2[(size_t)c * 32 + sl]);
            acc.x = fmaf(wv, hv.x, acc.x);
            acc.y = fmaf(wv, hv.y, acc.y);
        }
    }
    ((__half2*)agg)[(size_t)node * 32 + sl] = __floats2half2_rn(acc.x, acc.y);
}

// ---------------- final batched dot ----------------
__global__ void k_final(const __half* __restrict__ xh, const int* __restrict__ uidx,
                        const int* __restrict__ iidx, const float* __restrict__ Bu,
                        const float* __restrict__ Bi, const float* __restrict__ Mu,
                        float* __restrict__ out) {
    int t = threadIdx.x;
    int le = t >> 4, kq = t & 15, k0 = kq * 4;
    int i = blockIdx.x * 16 + le;
    if (i >= NBATCH) return;
    int u = uidx[i], it = iidx[i];
    float4 a = h4_to_f4(&xh[(size_t)u * 64 + k0]);
    float4 b = h4_to_f4(&xh[(size_t)(NUSERS + it) * 64 + k0]);
    float d = a.x * b.x + a.y * b.y + a.z * b.z + a.w * b.w;
#pragma unroll
    for (int m = 1; m < 16; m <<= 1) d += __shfl_xor(d, m, 64);
    if (kq == 0) out[i] = d + Bu[u] + Bi[it] + Mu[0];
}

extern "C" void kernel_launch(void* const* d_in, const int* in_sizes, int n_in,
                              void* d_out, int out_size, void* d_ws, size_t ws_size,
                              hipStream_t stream) {
    const float* Gu    = (const float*)d_in[0];
    const float* Gi    = (const float*)d_in[1];
    const float* Bu    = (const float*)d_in[2];
    const float* Bi    = (const float*)d_in[3];
    const float* Mu    = (const float*)d_in[4];
    const float* projW = (const float*)d_in[5];
    const float* projb = (const float*)d_in[6];
    const float* gcnW  = (const float*)d_in[7];
    const float* gcnb  = (const float*)d_in[8];
    const float* ef    = (const float*)d_in[9];
    const float* L0    = (const float*)d_in[10];
    const int*   erow  = (const int*)d_in[11];
    const int*   ecol  = (const int*)d_in[12];
    const int*   uidx  = (const int*)d_in[13];
    const int*   iidx  = (const int*)d_in[14];
    float* out = (float*)d_out;

    char* w = (char*)d_ws;
    size_t off = 0;
    auto take = [&](size_t bytes) -> void* {
        void* p = w + off;
        off += (bytes + 255) & ~(size_t)255;
        return p;
    };
    __half* xh    = (__half*)take((size_t)NNODES * KDIM * 2);
    __half* agg   = (__half*)take((size_t)NNODES * KDIM * 2);
    float*  v1p   = (float*)take((size_t)EH * 4);
    float*  v2p   = (float*)take((size_t)EH * 4);
    float*  deg   = (float*)take((size_t)NNODES * 4);
    int*    cntI  = (int*)take((size_t)NPAD_I * 4);   // adjacent with cntU: one zero pass
    int*    cntU  = (int*)take((size_t)NPAD_U * 4);
    int*    ofsI  = (int*)take((size_t)(NITEMS + 1) * 4);
    int*    curI  = (int*)take((size_t)(NITEMS + 1) * 4);
    int*    ofsU  = (int*)take((size_t)(NUSERS + 1) * 4);
    int*    curU  = (int*)take((size_t)(NUSERS + 1) * 4);
    int*    gcurI = (int*)take((size_t)NB * 4);
    int*    gcurU = (int*)take((size_t)NB * 4);
    int*    colp  = (int*)take((size_t)EH * 4);
    int*    eorig = (int*)take((size_t)EH * 4);
    int*    inv   = (int*)take((size_t)EH * 4);
    float2* L0p   = (float2*)take((size_t)EH * 8);
    int2*   csrU  = (int2*)take((size_t)EH * 8);
    __half* qp    = (__half*)take((size_t)EH * KDIM * 2);
    // CSR-build staging aliases qp (qp written only after both binB passes):
    // item staging [0,12MB), user staging [12MB,24MB) — qp region is 128MB.
    int*  srowI = (int*)qp;
    int2* spayI = (int2*)((char*)qp + (size_t)EH * 4);
    int*  srowU = (int*)((char*)qp + (size_t)EH * 12);
    int2* spayU = (int2*)((char*)qp + (size_t)EH * 16);

    // ---- init: zero cnt/deg, xh = fp16(concat(Gu,Gi)) ----
    k_init<<<(NNODES * KDIM / 4 + 255) / 256, 256, 0, stream>>>(Gu, Gi, xh, cntI, deg);

    // ---- CSR builds (layer-invariant): one fused edge pass ----
    k_count2<<<(EH + 255) / 256, 256, 0, stream>>>(erow, ecol, cntI, cntU);
    k_scan2<<<2, 1024, 0, stream>>>(cntI, ofsI, curI, cntU, ofsU, curU, gcurI, gcurU);
    k_binA2<<<256, 256, 0, stream>>>(erow, ecol, gcurI, gcurU, srowI, spayI, srowU, spayU);
    k_binB0<<<NB, 512, 0, stream>>>(srowI, spayI, ofsI, curI, L0, colp, eorig, inv, L0p);
    k_binB1<<<NB, 512, 0, stream>>>(srowU, spayU, ofsU, curU, inv, csrU);

    // qp[slot] = (ef[eorig[slot]] @ projW + projb)^2, fp16 (overwrites staging)
    k_gemm<1><<<1024, 256, 0, stream>>>(ef, projW, projb, qp, EH, eorig, nullptr);

    for (int l = 0; l < 3; ++l) {
        k_sim<<<(NITEMS + 3) / 4, 256, 0, stream>>>(xh, qp, colp, L0p, ofsI, v1p, v2p, deg);
        k_agg<<<IBLK + NUSERS / 8, 256, 0, stream>>>(ofsI, colp, v1p, ofsU, csrU, v2p,
                                                     deg, xh, agg);
        k_gemm<2><<<512, 256, 0, stream>>>(agg, gcnW + (size_t)l * 4096,
                                           gcnb + (size_t)l * 64, xh, NNODES, nullptr, deg);
    }
    k_final<<<(NBATCH + 15) / 16, 256, 0, stream>>>(xh, uidx, iidx, Bu, Bi, Mu, out);
}